// Round 1
// baseline (14476.102 us; speedup 1.0000x reference)
//
#include <hip/hip_runtime.h>
#include <math.h>

#define Bsz 128
#define Tsz 512
#define Esz 512
#define Hsz 1024
#define G4H 4096
#define Vsz 32000

typedef __attribute__((ext_vector_type(8))) short short8;
typedef __attribute__((ext_vector_type(8))) __bf16 bf16x8;
typedef __attribute__((ext_vector_type(4))) float f32x4;

__device__ inline unsigned short f2bf(float f) {
    unsigned u = __float_as_uint(f);
    u += 0x7fffu + ((u >> 16) & 1u);   // round-to-nearest-even
    return (unsigned short)(u >> 16);
}
__device__ inline float bf2f(unsigned short s) {
    return __uint_as_float(((unsigned)s) << 16);
}
__device__ inline f32x4 mfma16(short8 a, short8 b, f32x4 c) {
    return __builtin_amdgcn_mfma_f32_16x16x32_bf16(
        __builtin_bit_cast(bf16x8, a), __builtin_bit_cast(bf16x8, b), c, 0, 0, 0);
}

// ---------------- prep kernels ----------------
__global__ void k_prep_emb(const float* __restrict__ emb, unsigned short* __restrict__ dst) {
    size_t i = (size_t)blockIdx.x * 256 + threadIdx.x;
    if (i < (size_t)Vsz * Esz) dst[i] = f2bf(i < Esz ? 0.f : emb[i]);  // row 0 = PAD -> 0
}

__global__ void k_prep_w(const float* __restrict__ wi, const float* __restrict__ wf,
                         const float* __restrict__ wg, const float* __restrict__ wo,
                         int ncols, unsigned short* __restrict__ dst) {
    size_t i = (size_t)blockIdx.x * 256 + threadIdx.x;
    size_t per = (size_t)Hsz * ncols;
    if (i < 4 * per) {
        int g = (int)(i / per);
        size_t rem = i - (size_t)g * per;
        const float* src = g == 0 ? wi : g == 1 ? wf : g == 2 ? wg : wo;
        dst[i] = f2bf(src[rem]);
    }
}

__global__ void k_prep_misc(const float* __restrict__ bi, const float* __restrict__ bff,
                            const float* __restrict__ bg, const float* __restrict__ bo,
                            float* __restrict__ b4, unsigned short* __restrict__ hbuf,
                            float* __restrict__ cbuf, float* __restrict__ outh,
                            unsigned* __restrict__ bar) {
    int i = blockIdx.x * 256 + threadIdx.x;
    if (i < G4H) {
        const float* src = i < Hsz ? bi : i < 2 * Hsz ? bff : i < 3 * Hsz ? bg : bo;
        b4[i] = src[i & (Hsz - 1)];
    }
    if (i < 2 * Bsz * Hsz) hbuf[i] = 0;
    if (i < Bsz * Hsz) { cbuf[i] = 0.f; outh[i] = 0.f; }
    if (i < 2) bar[i] = 0u;
}

// ---------------- xp = emb[x] @ Wi^T + b  (bf16 MFMA, direct-global) ----------------
__global__ __launch_bounds__(256, 2) void xp_gemm(
    const unsigned short* __restrict__ emb16,   // [V][E] bf16
    const unsigned short* __restrict__ Wi16,    // [4H][E] bf16
    const float* __restrict__ b4,               // [4H]
    const int* __restrict__ x,                  // [B][T]
    unsigned short* __restrict__ xp,            // [TC][B][4H] bf16
    int t_base)
{
    const int tp = blockIdx.x;          // t' within chunk (covers all 128 b rows)
    const int n0 = blockIdx.y * 128;
    const int tid = threadIdx.x;
    const int w = tid >> 6, l = tid & 63;
    const int wm = w >> 1, wn = w & 1;
    const int lr = l & 15, lk = l >> 4;

    const unsigned short* arow[4];
    #pragma unroll
    for (int mt = 0; mt < 4; ++mt) {
        int b = wm * 64 + mt * 16 + lr;
        int xv = x[b * Tsz + t_base + tp];
        arow[mt] = emb16 + (size_t)xv * Esz + lk * 8;
    }
    const unsigned short* brow[4];
    #pragma unroll
    for (int nt = 0; nt < 4; ++nt) {
        int n = n0 + wn * 64 + nt * 16 + lr;
        brow[nt] = Wi16 + (size_t)n * Esz + lk * 8;
    }
    f32x4 acc[4][4] = {};
    #pragma unroll 2
    for (int k0 = 0; k0 < Esz; k0 += 32) {
        short8 av[4], bv[4];
        #pragma unroll
        for (int mt = 0; mt < 4; ++mt) av[mt] = *(const short8*)(arow[mt] + k0);
        #pragma unroll
        for (int nt = 0; nt < 4; ++nt) bv[nt] = *(const short8*)(brow[nt] + k0);
        #pragma unroll
        for (int mt = 0; mt < 4; ++mt)
            #pragma unroll
            for (int nt = 0; nt < 4; ++nt)
                acc[mt][nt] = mfma16(av[mt], bv[nt], acc[mt][nt]);
    }
    #pragma unroll
    for (int nt = 0; nt < 4; ++nt) {
        int n = n0 + wn * 64 + nt * 16 + lr;
        float bias = b4[n];
        #pragma unroll
        for (int mt = 0; mt < 4; ++mt) {
            #pragma unroll
            for (int r = 0; r < 4; ++r) {
                int b = wm * 64 + mt * 16 + lk * 4 + r;
                xp[((size_t)tp * Bsz + b) * G4H + n] = f2bf(acc[mt][nt][r] + bias);
            }
        }
    }
}

// ---------------- fused recurrence: z = xp_t + h @ Wh^T ; gates ; h,c update ----------------
// 128 persistent blocks; block owns 8 j-columns (x 4 gates = 32 Wh rows in LDS).
__global__ __launch_bounds__(256, 1) void lstm_steps(
    const unsigned short* __restrict__ Wh16,    // [4H][H] bf16
    const unsigned short* __restrict__ xp,      // [TC][B][4H] bf16
    const int* __restrict__ lengths,            // [B]
    unsigned short* __restrict__ hbuf,          // [2][B][H] bf16 (double buffer, parity = t&1)
    float* __restrict__ cbuf,                   // [B][H]
    float* __restrict__ outh,                   // [B][H]
    unsigned* __restrict__ bar,                 // [0]=counter [1]=generation
    int t0, int nsteps)
{
    __shared__ unsigned short Whs[32][1032];    // 32 rows x 1024 (+8 pad) bf16
    __shared__ float zs[128][33];               // z scratch, +1 pad
    const int tid = threadIdx.x;
    const int blk = blockIdx.x;
    const int j0 = blk * 8;

    // stage this block's 32 Wh rows (gate-major local row: r -> gate=r>>3, jj=r&7)
    for (int idx = tid; idx < 32 * 128; idx += 256) {
        int r = idx >> 7, ck = idx & 127;
        int grow = (r >> 3) * Hsz + j0 + (r & 7);
        *(short8*)&Whs[r][ck * 8] = *(const short8*)(Wh16 + (size_t)grow * Hsz + ck * 8);
    }
    float creg[8];
    int len = 0;
    if (tid < Bsz) {
        len = lengths[tid];
        #pragma unroll
        for (int jj = 0; jj < 8; ++jj) creg[jj] = cbuf[tid * Hsz + j0 + jj];
    }
    __syncthreads();

    const int w = tid >> 6, l = tid & 63, lr = l & 15, lk = l >> 4;
    const int row0 = w * 32 + lr, row1 = w * 32 + 16 + lr;

    for (int s = 0; s < nsteps; ++s) {
        const int t = t0 + s;
        const unsigned short* hsrc = hbuf + (size_t)(t & 1) * (Bsz * Hsz);
        f32x4 a00 = {}, a01 = {}, a10 = {}, a11 = {};
        #pragma unroll 4
        for (int kk = 0; kk < Hsz; kk += 32) {
            short8 av0 = *(const short8*)(hsrc + (size_t)row0 * Hsz + kk + lk * 8);
            short8 av1 = *(const short8*)(hsrc + (size_t)row1 * Hsz + kk + lk * 8);
            short8 bv0 = *(const short8*)&Whs[lr][kk + lk * 8];
            short8 bv1 = *(const short8*)&Whs[16 + lr][kk + lk * 8];
            a00 = mfma16(av0, bv0, a00);
            a01 = mfma16(av0, bv1, a01);
            a10 = mfma16(av1, bv0, a10);
            a11 = mfma16(av1, bv1, a11);
        }
        #pragma unroll
        for (int r = 0; r < 4; ++r) {
            zs[w * 32 + lk * 4 + r][lr]           = a00[r];
            zs[w * 32 + lk * 4 + r][16 + lr]      = a01[r];
            zs[w * 32 + 16 + lk * 4 + r][lr]      = a10[r];
            zs[w * 32 + 16 + lk * 4 + r][16 + lr] = a11[r];
        }
        __syncthreads();
        if (tid < Bsz) {
            const int b = tid;
            const unsigned short* xpb = xp + ((size_t)s * Bsz + b) * G4H + j0;
            short8 xi = *(const short8*)(xpb + 0 * Hsz);
            short8 xf = *(const short8*)(xpb + 1 * Hsz);
            short8 xg = *(const short8*)(xpb + 2 * Hsz);
            short8 xo = *(const short8*)(xpb + 3 * Hsz);
            float hnew[8];
            unsigned short h16[8];
            #pragma unroll
            for (int jj = 0; jj < 8; ++jj) {
                float zi = zs[b][jj]      + bf2f((unsigned short)xi[jj]);
                float zf = zs[b][8 + jj]  + bf2f((unsigned short)xf[jj]);
                float zg = zs[b][16 + jj] + bf2f((unsigned short)xg[jj]);
                float zo = zs[b][24 + jj] + bf2f((unsigned short)xo[jj]);
                float it = 1.f / (1.f + expf(-zi));
                float ft = 1.f / (1.f + expf(-zf));
                float gt = tanhf(zg);
                float ot = 1.f / (1.f + expf(-zo));
                float c = ft * creg[jj] + it * gt;
                creg[jj] = c;
                float h = ot * tanhf(c);
                hnew[jj] = h;
                h16[jj] = f2bf(h);
            }
            unsigned short* hd = hbuf + (size_t)((t + 1) & 1) * (Bsz * Hsz) + (size_t)b * Hsz + j0;
            short8 hv;
            #pragma unroll
            for (int jj = 0; jj < 8; ++jj) hv[jj] = (short)h16[jj];
            *(short8*)hd = hv;
            if (len == t + 1) {
                #pragma unroll
                for (int jj = 0; jj < 8; ++jj) outh[(size_t)b * Hsz + j0 + jj] = hnew[jj];
            }
        }
        // ---- grid barrier (device-scope, 128 blocks, co-resident) ----
        __syncthreads();
        if (tid == 0) {
            __threadfence();   // release: write back dirty L2 (h slice) to device scope
            unsigned g = __hip_atomic_load(bar + 1, __ATOMIC_RELAXED, __HIP_MEMORY_SCOPE_AGENT);
            unsigned a = __hip_atomic_fetch_add(bar, 1u, __ATOMIC_ACQ_REL, __HIP_MEMORY_SCOPE_AGENT);
            if (a == 127u) {
                __hip_atomic_store(bar, 0u, __ATOMIC_RELAXED, __HIP_MEMORY_SCOPE_AGENT);
                __hip_atomic_fetch_add(bar + 1, 1u, __ATOMIC_RELEASE, __HIP_MEMORY_SCOPE_AGENT);
            } else {
                while (__hip_atomic_load(bar + 1, __ATOMIC_RELAXED, __HIP_MEMORY_SCOPE_AGENT) == g) {
                    __builtin_amdgcn_s_sleep(2);
                }
            }
            __threadfence();   // acquire: invalidate caches so fresh h is visible
        }
        __syncthreads();
    }
    if (tid < Bsz) {
        #pragma unroll
        for (int jj = 0; jj < 8; ++jj) cbuf[tid * Hsz + j0 + jj] = creg[jj];
    }
}

// ---------------- final fc: out[b] = fc_w . outh[b] + fc_b ----------------
__global__ __launch_bounds__(64) void k_fc(const float* __restrict__ outh,
                                           const float* __restrict__ fc_w,
                                           const float* __restrict__ fc_b,
                                           float* __restrict__ out) {
    int b = blockIdx.x, l = threadIdx.x;
    float s = 0.f;
    for (int k = l; k < Hsz; k += 64) s += outh[(size_t)b * Hsz + k] * fc_w[k];
    #pragma unroll
    for (int o = 32; o > 0; o >>= 1) s += __shfl_down(s, o);
    if (l == 0) out[b] = s + fc_b[0];
}

extern "C" void kernel_launch(void* const* d_in, const int* in_sizes, int n_in,
                              void* d_out, int out_size, void* d_ws, size_t ws_size,
                              hipStream_t stream) {
    const int* x       = (const int*)d_in[0];
    const int* lengths = (const int*)d_in[1];
    const float* emb   = (const float*)d_in[2];
    const float* W_ii  = (const float*)d_in[3];
    const float* W_hi  = (const float*)d_in[4];
    const float* b_i   = (const float*)d_in[5];
    const float* W_if  = (const float*)d_in[6];
    const float* W_hf  = (const float*)d_in[7];
    const float* b_f   = (const float*)d_in[8];
    const float* W_ig  = (const float*)d_in[9];
    const float* W_hg  = (const float*)d_in[10];
    const float* b_g   = (const float*)d_in[11];
    const float* W_io  = (const float*)d_in[12];
    const float* W_ho  = (const float*)d_in[13];
    const float* b_o   = (const float*)d_in[14];
    const float* fc_w  = (const float*)d_in[15];
    const float* fc_b  = (const float*)d_in[16];
    float* out = (float*)d_out;

    char* ws = (char*)d_ws;
    size_t off = 0;
    auto take = [&](size_t bytes) { size_t o = off; off += (bytes + 255) & ~(size_t)255; return o; };
    unsigned* bar         = (unsigned*)(ws + take(256));
    unsigned short* hbuf  = (unsigned short*)(ws + take((size_t)2 * Bsz * Hsz * 2));
    float* cbuf           = (float*)(ws + take((size_t)Bsz * Hsz * 4));
    float* outh           = (float*)(ws + take((size_t)Bsz * Hsz * 4));
    float* b4             = (float*)(ws + take((size_t)G4H * 4));
    unsigned short* Wi16  = (unsigned short*)(ws + take((size_t)G4H * Esz * 2));
    unsigned short* Wh16  = (unsigned short*)(ws + take((size_t)G4H * Hsz * 2));
    unsigned short* emb16 = (unsigned short*)(ws + take((size_t)Vsz * Esz * 2));
    size_t fixed = off;

    int TC = 128;   // timestep chunk; xp chunk buffer = TC MB (bf16)
    while (TC > 1 && fixed + (size_t)TC * Bsz * G4H * 2 > ws_size) TC >>= 1;
    unsigned short* xp = (unsigned short*)(ws + take((size_t)TC * Bsz * G4H * 2));

    k_prep_emb<<<(Vsz * Esz + 255) / 256, 256, 0, stream>>>(emb, emb16);
    k_prep_w<<<(4 * Hsz * Esz + 255) / 256, 256, 0, stream>>>(W_ii, W_if, W_ig, W_io, Esz, Wi16);
    k_prep_w<<<(4 * Hsz * Hsz + 255) / 256, 256, 0, stream>>>(W_hi, W_hf, W_hg, W_ho, Hsz, Wh16);
    k_prep_misc<<<(2 * Bsz * Hsz + 255) / 256, 256, 0, stream>>>(b_i, b_f, b_g, b_o, b4, hbuf, cbuf, outh, bar);

    for (int c = 0; c < Tsz / TC; ++c) {
        dim3 g(TC, 32);
        xp_gemm<<<g, 256, 0, stream>>>(emb16, Wi16, b4, x, xp, c * TC);
        lstm_steps<<<128, 256, 0, stream>>>(Wh16, xp, lengths, hbuf, cbuf, outh, bar, c * TC, TC);
    }
    k_fc<<<Bsz, 64, 0, stream>>>(outh, fc_w, fc_b, out);
}

// Round 3
// 12939.363 us; speedup vs baseline: 1.1188x; 1.1188x over previous
//
#include <hip/hip_runtime.h>
#include <math.h>

#define Bsz 128
#define Tsz 512
#define Esz 512
#define Hsz 1024
#define G4H 4096
#define Vsz 32000
#define NB  128          // lstm blocks (1/CU on half the chip)
#define BH  (Bsz * Hsz)

typedef __attribute__((ext_vector_type(8))) short short8;
typedef __attribute__((ext_vector_type(8))) __bf16 bf16x8;
typedef __attribute__((ext_vector_type(4))) float f32x4;
typedef __attribute__((ext_vector_type(4))) unsigned int uint4v;

__device__ inline unsigned short f2bf(float f) {
    unsigned u = __float_as_uint(f);
    u += 0x7fffu + ((u >> 16) & 1u);   // RTNE
    return (unsigned short)(u >> 16);
}
__device__ inline float bf2f(unsigned short s) {
    return __uint_as_float(((unsigned)s) << 16);
}
__device__ inline f32x4 mfma16(short8 a, short8 b, f32x4 c) {
    return __builtin_amdgcn_mfma_f32_16x16x32_bf16(
        __builtin_bit_cast(bf16x8, a), __builtin_bit_cast(bf16x8, b), c, 0, 0, 0);
}

// one cached async 16B load; early-clobber so dst never aliases addr regs
#define GLD16(dst, p)                                                      \
    asm volatile("global_load_dwordx4 %0, %1, off" : "=&v"(dst) : "v"(p))

#define WAITVM(n)                                                          \
    do { asm volatile("s_waitcnt vmcnt(" #n ")" ::: "memory");             \
         __builtin_amdgcn_sched_barrier(0); } while (0)

// device-coherent write-through store of one bf16 (low 16 bits of v)
#define STORE_H16(p, v)                                                    \
    asm volatile("global_store_short %0, %1, off sc0 sc1" ::"v"(p), "v"(v) : "memory")

// ---------------- prep kernels ----------------
__global__ void k_prep_emb(const float* __restrict__ emb, unsigned short* __restrict__ dst) {
    size_t i = (size_t)blockIdx.x * 256 + threadIdx.x;
    if (i < (size_t)Vsz * Esz) dst[i] = f2bf(i < Esz ? 0.f : emb[i]);  // row 0 = PAD -> 0
}

__global__ void k_prep_w(const float* __restrict__ wi, const float* __restrict__ wf,
                         const float* __restrict__ wg, const float* __restrict__ wo,
                         int ncols, unsigned short* __restrict__ dst) {
    size_t i = (size_t)blockIdx.x * 256 + threadIdx.x;
    size_t per = (size_t)Hsz * ncols;
    if (i < 4 * per) {
        int g = (int)(i / per);
        size_t rem = i - (size_t)g * per;
        const float* src = g == 0 ? wi : g == 1 ? wf : g == 2 ? wg : wo;
        dst[i] = f2bf(src[rem]);
    }
}

__global__ void k_prep_misc(const float* __restrict__ bi, const float* __restrict__ bff,
                            const float* __restrict__ bg, const float* __restrict__ bo,
                            float* __restrict__ b4, unsigned short* __restrict__ hbuf,
                            float* __restrict__ cbuf, float* __restrict__ outh,
                            unsigned long long* __restrict__ bar) {
    int i = blockIdx.x * 256 + threadIdx.x;
    if (i < G4H) {
        const float* src = i < Hsz ? bi : i < 2 * Hsz ? bff : i < 3 * Hsz ? bg : bo;
        b4[i] = src[i & (Hsz - 1)];
    }
    if (i < 2 * Bsz * Hsz) hbuf[i] = 0;
    if (i < Bsz * Hsz) { cbuf[i] = 0.f; outh[i] = 0.f; }
    if (i == 0) *bar = 0ull;
}

// ---------------- xp = emb[x] @ Wi^T + b  (verified in R1) ----------------
__global__ __launch_bounds__(256, 2) void xp_gemm(
    const unsigned short* __restrict__ emb16, const unsigned short* __restrict__ Wi16,
    const float* __restrict__ b4, const int* __restrict__ x,
    unsigned short* __restrict__ xp, int t_base)
{
    const int tp = blockIdx.x;
    const int n0 = blockIdx.y * 128;
    const int tid = threadIdx.x;
    const int w = tid >> 6, l = tid & 63;
    const int wm = w >> 1, wn = w & 1;
    const int lr = l & 15, lk = l >> 4;

    const unsigned short* arow[4];
    #pragma unroll
    for (int mt = 0; mt < 4; ++mt) {
        int b = wm * 64 + mt * 16 + lr;
        int xv = x[b * Tsz + t_base + tp];
        arow[mt] = emb16 + (size_t)xv * Esz + lk * 8;
    }
    const unsigned short* brow[4];
    #pragma unroll
    for (int nt = 0; nt < 4; ++nt) {
        int n = n0 + wn * 64 + nt * 16 + lr;
        brow[nt] = Wi16 + (size_t)n * Esz + lk * 8;
    }
    f32x4 acc[4][4] = {};
    #pragma unroll 2
    for (int k0 = 0; k0 < Esz; k0 += 32) {
        short8 av[4], bv[4];
        #pragma unroll
        for (int mt = 0; mt < 4; ++mt) av[mt] = *(const short8*)(arow[mt] + k0);
        #pragma unroll
        for (int nt = 0; nt < 4; ++nt) bv[nt] = *(const short8*)(brow[nt] + k0);
        #pragma unroll
        for (int mt = 0; mt < 4; ++mt)
            #pragma unroll
            for (int nt = 0; nt < 4; ++nt)
                acc[mt][nt] = mfma16(av[mt], bv[nt], acc[mt][nt]);
    }
    #pragma unroll
    for (int nt = 0; nt < 4; ++nt) {
        int n = n0 + wn * 64 + nt * 16 + lr;
        float bias = b4[n];
        #pragma unroll
        for (int mt = 0; mt < 4; ++mt) {
            #pragma unroll
            for (int r = 0; r < 4; ++r) {
                int b = wm * 64 + mt * 16 + lk * 4 + r;
                xp[((size_t)tp * Bsz + b) * G4H + n] = f2bf(acc[mt][nt][r] + bias);
            }
        }
    }
}

// ---------------- fused recurrence ----------------
// 128 blocks x 4 waves (256 thr). Block owns 8 h-cols (j0) x 4 gates = 32 Wh rows in LDS.
// Wave w: batch rows 32w..32w+31 (2 A-tiles) x all 32 cols (2 B-tiles), 2x2 f32x4 acc.
// h reads: cached (L2 shared per XCD); freshness via per-step agent acquire fence.
// h writes: sc0sc1 write-through; drained by vmcnt(0) in __syncthreads before arrive.
__global__ __launch_bounds__(256, 1) void lstm_steps(
    const unsigned short* __restrict__ Wh16,
    const unsigned short* __restrict__ xp,
    const int* __restrict__ lengths,
    unsigned short* __restrict__ hbuf,     // [2][B][H] bf16 double buffer
    float* __restrict__ cbuf,
    float* __restrict__ outh,
    unsigned long long* __restrict__ bar,  // packed {gen:32, count:32}
    int t0, int nsteps)
{
    __shared__ unsigned short Whs[32][1032];   // 32 rows x 1024 (+8 pad) bf16 = 66 KB
    const int tid = threadIdx.x;
    const int blk = blockIdx.x;
    const int j0 = blk * 8;

    // stage Wh slice: local row n -> gate n>>3, col j0+(n&7)
    for (int idx = tid; idx < 32 * 128; idx += 256) {
        int n = idx >> 7, ck = idx & 127;
        int grow = (n >> 3) * Hsz + j0 + (n & 7);
        *(short8*)&Whs[n][ck * 8] = *(const short8*)(Wh16 + (size_t)grow * Hsz + ck * 8);
    }

    const int w = tid >> 6, l = tid & 63, lr = l & 15, lk = l >> 4;
    const bool own = (lr < 8);
    const int jj = lr & 7;

    int lenr[2][4];
    float creg[2][4];
    #pragma unroll
    for (int mi = 0; mi < 2; ++mi)
        #pragma unroll
        for (int r = 0; r < 4; ++r) {
            int b = 32 * w + mi * 16 + 4 * lk + r;
            lenr[mi][r] = own ? lengths[b] : 0;
            creg[mi][r] = own ? cbuf[(size_t)b * Hsz + j0 + jj] : 0.f;
        }
    __syncthreads();

    const int rowA0 = 32 * w + lr;          // A-tile 0 row this lane loads
    const int rowA1 = rowA0 + 16;           // A-tile 1

#define ISSUE_CHUNK(buf, kc_) do {                                         \
        GLD16(buf[0], ap0 + (kc_) * 128 + 0);                              \
        GLD16(buf[1], ap0 + (kc_) * 128 + 32);                             \
        GLD16(buf[2], ap0 + (kc_) * 128 + 64);                             \
        GLD16(buf[3], ap0 + (kc_) * 128 + 96);                             \
        GLD16(buf[4], ap1 + (kc_) * 128 + 0);                              \
        GLD16(buf[5], ap1 + (kc_) * 128 + 32);                             \
        GLD16(buf[6], ap1 + (kc_) * 128 + 64);                             \
        GLD16(buf[7], ap1 + (kc_) * 128 + 96);                             \
    } while (0)

#define CONSUME(buf, kc_) do {                                             \
        _Pragma("unroll")                                                  \
        for (int ks_ = 0; ks_ < 4; ++ks_) {                                \
            const int kb_ = (kc_) * 128 + ks_ * 32 + lk * 8;               \
            short8 bv0_ = *(const short8*)&Whs[lr][kb_];                   \
            short8 bv1_ = *(const short8*)&Whs[16 + lr][kb_];              \
            short8 a0_ = __builtin_bit_cast(short8, buf[ks_]);             \
            short8 a1_ = __builtin_bit_cast(short8, buf[4 + ks_]);         \
            acc00 = mfma16(a0_, bv0_, acc00);                              \
            acc01 = mfma16(a0_, bv1_, acc01);                              \
            acc10 = mfma16(a1_, bv0_, acc10);                              \
            acc11 = mfma16(a1_, bv1_, acc11);                              \
        }                                                                  \
    } while (0)

    for (int s = 0; s < nsteps; ++s) {
        const int t = t0 + s;
        const unsigned short* hsrc = hbuf + (size_t)(t & 1) * BH;
        const unsigned short* ap0 = hsrc + (size_t)rowA0 * Hsz + lk * 8;
        const unsigned short* ap1 = hsrc + (size_t)rowA1 * Hsz + lk * 8;

        // xp prefetch (owners only); latency hides under K-loop
        float xv[2][4][4];
        #pragma unroll
        for (int mi = 0; mi < 2; ++mi)
            #pragma unroll
            for (int r = 0; r < 4; ++r) {
                if (own) {
                    int b = 32 * w + mi * 16 + 4 * lk + r;
                    const unsigned short* xb = xp + ((size_t)s * Bsz + b) * G4H + j0 + jj;
                    xv[mi][r][0] = bf2f(xb[0 * Hsz]);
                    xv[mi][r][1] = bf2f(xb[1 * Hsz]);
                    xv[mi][r][2] = bf2f(xb[2 * Hsz]);
                    xv[mi][r][3] = bf2f(xb[3 * Hsz]);
                } else {
                    xv[mi][r][0] = xv[mi][r][1] = xv[mi][r][2] = xv[mi][r][3] = 0.f;
                }
            }

        f32x4 acc00 = {}, acc01 = {}, acc10 = {}, acc11 = {};
        uint4v A[8], Bb[8];
        // software pipeline: wait-then-consume; every WAITVM(8) has >=8 younger vmem ops
        ISSUE_CHUNK(A, 0);  ISSUE_CHUNK(Bb, 1);
        WAITVM(8);  CONSUME(A, 0);   ISSUE_CHUNK(A, 2);
        WAITVM(8);  CONSUME(Bb, 1);  ISSUE_CHUNK(Bb, 3);
        WAITVM(8);  CONSUME(A, 2);   ISSUE_CHUNK(A, 4);
        WAITVM(8);  CONSUME(Bb, 3);  ISSUE_CHUNK(Bb, 5);
        WAITVM(8);  CONSUME(A, 4);   ISSUE_CHUNK(A, 6);
        WAITVM(8);  CONSUME(Bb, 5);  ISSUE_CHUNK(Bb, 7);
        WAITVM(8);  CONSUME(A, 6);
        WAITVM(0);  CONSUME(Bb, 7);

        // gates fully in registers; partner lane lr+8 holds f/o partials
        #pragma unroll
        for (int mi = 0; mi < 2; ++mi) {
            f32x4 aIF = mi ? acc10 : acc00;
            f32x4 aGO = mi ? acc11 : acc01;
            #pragma unroll
            for (int r = 0; r < 4; ++r) {
                float zfp = __shfl_xor(aIF[r], 8);
                float zop = __shfl_xor(aGO[r], 8);
                if (own) {
                    int b = 32 * w + mi * 16 + 4 * lk + r;
                    float zi = aIF[r] + xv[mi][r][0];
                    float zf = zfp    + xv[mi][r][1];
                    float zg = aGO[r] + xv[mi][r][2];
                    float zo = zop    + xv[mi][r][3];
                    float it = 1.f / (1.f + __expf(-zi));
                    float ft = 1.f / (1.f + __expf(-zf));
                    float gt = tanhf(zg);
                    float ot = 1.f / (1.f + __expf(-zo));
                    float c = ft * creg[mi][r] + it * gt;
                    creg[mi][r] = c;
                    float h = ot * tanhf(c);
                    if (lenr[mi][r] == t + 1) outh[(size_t)b * Hsz + j0 + jj] = h;
                    unsigned hv = f2bf(h);
                    unsigned short* hd = hbuf + (size_t)((t + 1) & 1) * BH
                                       + (size_t)b * Hsz + j0 + jj;
                    STORE_H16(hd, hv);
                }
            }
        }

        // ---- grid barrier (single u64 {gen,count}, relaxed) ----
        __syncthreads();   // implies vmcnt(0): write-through h stores ACKed at coherent point
        if (tid == 0) {
            unsigned long long v = __hip_atomic_load(bar, __ATOMIC_RELAXED, __HIP_MEMORY_SCOPE_AGENT);
            unsigned gen = (unsigned)(v >> 32);
            unsigned long long old = __hip_atomic_fetch_add(bar, 1ull, __ATOMIC_RELAXED, __HIP_MEMORY_SCOPE_AGENT);
            if ((unsigned)old == NB - 1u) {
                // +((1<<32)-NB): count wraps to 0, carry bumps gen, in one atomic
                __hip_atomic_fetch_add(bar, (1ull << 32) - (unsigned long long)NB,
                                       __ATOMIC_RELAXED, __HIP_MEMORY_SCOPE_AGENT);
            } else {
                unsigned long long cur;
                do {
                    __builtin_amdgcn_s_sleep(2);
                    cur = __hip_atomic_load(bar, __ATOMIC_RELAXED, __HIP_MEMORY_SCOPE_AGENT);
                } while ((unsigned)(cur >> 32) == gen);
            }
        }
        __syncthreads();
        // per-wave device acquire: invalidate L1 + XCD L2 so next step's cached
        // h loads see the write-through data (compiler emits the correct inv)
        __builtin_amdgcn_fence(__ATOMIC_ACQUIRE, "agent");
    }

    #pragma unroll
    for (int mi = 0; mi < 2; ++mi)
        #pragma unroll
        for (int r = 0; r < 4; ++r)
            if (own) {
                int b = 32 * w + mi * 16 + 4 * lk + r;
                cbuf[(size_t)b * Hsz + j0 + jj] = creg[mi][r];
            }
#undef ISSUE_CHUNK
#undef CONSUME
}

// ---------------- final fc ----------------
__global__ __launch_bounds__(64) void k_fc(const float* __restrict__ outh,
                                           const float* __restrict__ fc_w,
                                           const float* __restrict__ fc_b,
                                           float* __restrict__ out) {
    int b = blockIdx.x, l = threadIdx.x;
    float s = 0.f;
    for (int k = l; k < Hsz; k += 64) s += outh[(size_t)b * Hsz + k] * fc_w[k];
    #pragma unroll
    for (int o = 32; o > 0; o >>= 1) s += __shfl_down(s, o);
    if (l == 0) out[b] = s + fc_b[0];
}

extern "C" void kernel_launch(void* const* d_in, const int* in_sizes, int n_in,
                              void* d_out, int out_size, void* d_ws, size_t ws_size,
                              hipStream_t stream) {
    const int* x       = (const int*)d_in[0];
    const int* lengths = (const int*)d_in[1];
    const float* emb   = (const float*)d_in[2];
    const float* W_ii  = (const float*)d_in[3];
    const float* W_hi  = (const float*)d_in[4];
    const float* b_i   = (const float*)d_in[5];
    const float* W_if  = (const float*)d_in[6];
    const float* W_hf  = (const float*)d_in[7];
    const float* b_f   = (const float*)d_in[8];
    const float* W_ig  = (const float*)d_in[9];
    const float* W_hg  = (const float*)d_in[10];
    const float* b_g   = (const float*)d_in[11];
    const float* W_io  = (const float*)d_in[12];
    const float* W_ho  = (const float*)d_in[13];
    const float* b_o   = (const float*)d_in[14];
    const float* fc_w  = (const float*)d_in[15];
    const float* fc_b  = (const float*)d_in[16];
    float* out = (float*)d_out;

    char* ws = (char*)d_ws;
    size_t off = 0;
    auto take = [&](size_t bytes) { size_t o = off; off += (bytes + 255) & ~(size_t)255; return o; };
    unsigned long long* bar = (unsigned long long*)(ws + take(256));
    unsigned short* hbuf  = (unsigned short*)(ws + take((size_t)2 * Bsz * Hsz * 2));
    float* cbuf           = (float*)(ws + take((size_t)Bsz * Hsz * 4));
    float* outh           = (float*)(ws + take((size_t)Bsz * Hsz * 4));
    float* b4             = (float*)(ws + take((size_t)G4H * 4));
    unsigned short* Wi16  = (unsigned short*)(ws + take((size_t)G4H * Esz * 2));
    unsigned short* Wh16  = (unsigned short*)(ws + take((size_t)G4H * Hsz * 2));
    unsigned short* emb16 = (unsigned short*)(ws + take((size_t)Vsz * Esz * 2));
    size_t fixed = off;

    int TC = 128;
    while (TC > 1 && fixed + (size_t)TC * Bsz * G4H * 2 > ws_size) TC >>= 1;
    unsigned short* xp = (unsigned short*)(ws + take((size_t)TC * Bsz * G4H * 2));

    k_prep_emb<<<(Vsz * Esz + 255) / 256, 256, 0, stream>>>(emb, emb16);
    k_prep_w<<<(4 * Hsz * Esz + 255) / 256, 256, 0, stream>>>(W_ii, W_if, W_ig, W_io, Esz, Wi16);
    k_prep_w<<<(4 * Hsz * Hsz + 255) / 256, 256, 0, stream>>>(W_hi, W_hf, W_hg, W_ho, Hsz, Wh16);
    k_prep_misc<<<(2 * Bsz * Hsz + 255) / 256, 256, 0, stream>>>(b_i, b_f, b_g, b_o, b4, hbuf, cbuf, outh, bar);

    for (int c = 0; c < Tsz / TC; ++c) {
        dim3 g(TC, 32);
        xp_gemm<<<g, 256, 0, stream>>>(emb16, Wi16, b4, x, xp, c * TC);
        lstm_steps<<<NB, 256, 0, stream>>>(Wh16, xp, lengths, hbuf, cbuf, outh, bar, c * TC, TC);
    }
    k_fc<<<Bsz, 64, 0, stream>>>(outh, fc_w, fc_b, out);
}

// Round 4
// 10777.589 us; speedup vs baseline: 1.3432x; 1.2006x over previous
//
#include <hip/hip_runtime.h>
#include <math.h>

#define Bsz 128
#define Tsz 512
#define Esz 512
#define Hsz 1024
#define G4H 4096
#define Vsz 32000
#define NB  128          // lstm blocks
#define BH  (Bsz * Hsz)

typedef __attribute__((ext_vector_type(8))) short short8;
typedef __attribute__((ext_vector_type(8))) __bf16 bf16x8;
typedef __attribute__((ext_vector_type(4))) float f32x4;
typedef __attribute__((ext_vector_type(4))) unsigned int uint4v;

__device__ inline unsigned short f2bf(float f) {
    unsigned u = __float_as_uint(f);
    u += 0x7fffu + ((u >> 16) & 1u);   // RTNE
    return (unsigned short)(u >> 16);
}
__device__ inline float bf2f(unsigned short s) {
    return __uint_as_float(((unsigned)s) << 16);
}
__device__ inline f32x4 mfma16(short8 a, short8 b, f32x4 c) {
    return __builtin_amdgcn_mfma_f32_16x16x32_bf16(
        __builtin_bit_cast(bf16x8, a), __builtin_bit_cast(bf16x8, b), c, 0, 0, 0);
}

// one cached async 16B load; early-clobber so dst never aliases addr regs
#define GLD16(dst, p)                                                      \
    asm volatile("global_load_dwordx4 %0, %1, off" : "=&v"(dst) : "v"(p))

#define WAITVM(n)                                                          \
    do { asm volatile("s_waitcnt vmcnt(" #n ")" ::: "memory");             \
         __builtin_amdgcn_sched_barrier(0); } while (0)

// device-coherent write-through store of one bf16 (low 16 bits of v)
#define STORE_H16(p, v)                                                    \
    asm volatile("global_store_short %0, %1, off sc0 sc1" ::"v"(p), "v"(v) : "memory")

// ---------------- prep kernels ----------------
__global__ void k_prep_emb(const float* __restrict__ emb, unsigned short* __restrict__ dst) {
    size_t i = (size_t)blockIdx.x * 256 + threadIdx.x;
    if (i < (size_t)Vsz * Esz) dst[i] = f2bf(i < Esz ? 0.f : emb[i]);  // row 0 = PAD -> 0
}

__global__ void k_prep_w(const float* __restrict__ wi, const float* __restrict__ wf,
                         const float* __restrict__ wg, const float* __restrict__ wo,
                         int ncols, unsigned short* __restrict__ dst) {
    size_t i = (size_t)blockIdx.x * 256 + threadIdx.x;
    size_t per = (size_t)Hsz * ncols;
    if (i < 4 * per) {
        int g = (int)(i / per);
        size_t rem = i - (size_t)g * per;
        const float* src = g == 0 ? wi : g == 1 ? wf : g == 2 ? wg : wo;
        dst[i] = f2bf(src[rem]);
    }
}

__global__ void k_prep_misc(const float* __restrict__ bi, const float* __restrict__ bff,
                            const float* __restrict__ bg, const float* __restrict__ bo,
                            float* __restrict__ b4, unsigned short* __restrict__ hbuf,
                            float* __restrict__ cbuf, float* __restrict__ outh,
                            unsigned long long* __restrict__ bar) {
    int i = blockIdx.x * 256 + threadIdx.x;
    if (i < G4H) {
        const float* src = i < Hsz ? bi : i < 2 * Hsz ? bff : i < 3 * Hsz ? bg : bo;
        b4[i] = src[i & (Hsz - 1)];
    }
    if (i < 2 * Bsz * Hsz) hbuf[i] = 0;
    if (i < Bsz * Hsz) { cbuf[i] = 0.f; outh[i] = 0.f; }
    if (i == 0) *bar = 0ull;
}

// ---------------- xp = emb[x] @ Wi^T + b ----------------
// Output layout: xp[t'][blk][b][gate][jj]  (blk = gate-col j/8, jj = j%8)
// -> each lstm block's per-step slice is contiguous 8 KB.
__global__ __launch_bounds__(256, 2) void xp_gemm(
    const unsigned short* __restrict__ emb16, const unsigned short* __restrict__ Wi16,
    const float* __restrict__ b4, const int* __restrict__ x,
    unsigned short* __restrict__ xp, int t_base)
{
    const int tp = blockIdx.x;
    const int n0 = blockIdx.y * 128;
    const int tid = threadIdx.x;
    const int w = tid >> 6, l = tid & 63;
    const int wm = w >> 1, wn = w & 1;
    const int lr = l & 15, lk = l >> 4;

    const unsigned short* arow[4];
    #pragma unroll
    for (int mt = 0; mt < 4; ++mt) {
        int b = wm * 64 + mt * 16 + lr;
        int xv = x[b * Tsz + t_base + tp];
        arow[mt] = emb16 + (size_t)xv * Esz + lk * 8;
    }
    const unsigned short* brow[4];
    #pragma unroll
    for (int nt = 0; nt < 4; ++nt) {
        int n = n0 + wn * 64 + nt * 16 + lr;
        brow[nt] = Wi16 + (size_t)n * Esz + lk * 8;
    }
    f32x4 acc[4][4] = {};
    #pragma unroll 2
    for (int k0 = 0; k0 < Esz; k0 += 32) {
        short8 av[4], bv[4];
        #pragma unroll
        for (int mt = 0; mt < 4; ++mt) av[mt] = *(const short8*)(arow[mt] + k0);
        #pragma unroll
        for (int nt = 0; nt < 4; ++nt) bv[nt] = *(const short8*)(brow[nt] + k0);
        #pragma unroll
        for (int mt = 0; mt < 4; ++mt)
            #pragma unroll
            for (int nt = 0; nt < 4; ++nt)
                acc[mt][nt] = mfma16(av[mt], bv[nt], acc[mt][nt]);
    }
    #pragma unroll
    for (int nt = 0; nt < 4; ++nt) {
        int n = n0 + wn * 64 + nt * 16 + lr;
        float bias = b4[n];
        int g = n >> 10, j = n & 1023;
        int bk = j >> 3, jj = j & 7;
        #pragma unroll
        for (int mt = 0; mt < 4; ++mt) {
            #pragma unroll
            for (int r = 0; r < 4; ++r) {
                int b = wm * 64 + mt * 16 + lk * 4 + r;
                xp[(((size_t)tp * NB + bk) * Bsz + b) * 32 + g * 8 + jj] =
                    f2bf(acc[mt][nt][r] + bias);
            }
        }
    }
}

// ---------------- fused recurrence ----------------
// 128 blocks x 4 waves. Block owns 8 h-cols (j0) x 4 gates = 32 Wh rows in LDS.
// xp slice for step s+1 staged global->LDS during the barrier wait (LDS survives
// the per-step agent acquire fence, so post-fence we never touch global xp).
__global__ __launch_bounds__(256, 1) void lstm_steps(
    const unsigned short* __restrict__ Wh16,
    const unsigned short* __restrict__ xp,    // [T'][NB][B][4][8] bf16
    const int* __restrict__ lengths,
    unsigned short* __restrict__ hbuf,        // [2][B][H] bf16 double buffer
    float* __restrict__ cbuf,
    float* __restrict__ outh,
    unsigned long long* __restrict__ bar,     // packed {gen:32, count:32}
    int t0, int nsteps)
{
    __shared__ unsigned short Whs[32][1032];   // 66 KB
    __shared__ unsigned short xps[Bsz * 32];   // 8 KB: [b][gate][jj] for current step
    const int tid = threadIdx.x;
    const int blk = blockIdx.x;
    const int j0 = blk * 8;

    // stage Wh slice: local row n -> gate n>>3, col j0+(n&7)
    for (int idx = tid; idx < 32 * 128; idx += 256) {
        int n = idx >> 7, ck = idx & 127;
        int grow = (n >> 3) * Hsz + j0 + (n & 7);
        *(short8*)&Whs[n][ck * 8] = *(const short8*)(Wh16 + (size_t)grow * Hsz + ck * 8);
    }

    const int w = tid >> 6, l = tid & 63, lr = l & 15, lk = l >> 4;
    const bool own = (lr < 8);
    const int jj = lr & 7;

    int lenr[2][4];
    float creg[2][4];
    #pragma unroll
    for (int mi = 0; mi < 2; ++mi)
        #pragma unroll
        for (int r = 0; r < 4; ++r) {
            int b = 32 * w + mi * 16 + 4 * lk + r;
            lenr[mi][r] = own ? lengths[b] : 0;
            creg[mi][r] = own ? cbuf[(size_t)b * Hsz + j0 + jj] : 0.f;
        }

    // prologue: stage xp slice for s=0
    {
        const short8* sp = (const short8*)(xp + ((size_t)0 * NB + blk) * ((size_t)Bsz * 32));
        short8 v0 = sp[tid * 2], v1 = sp[tid * 2 + 1];
        *(short8*)&xps[tid * 16] = v0;
        *(short8*)&xps[tid * 16 + 8] = v1;
    }
    __syncthreads();

    const int rowA0 = 32 * w + lr;
    const int rowA1 = rowA0 + 16;

#define ISSUE_CHUNK(buf, kc_) do {                                         \
        GLD16(buf[0], ap0 + (kc_) * 128 + 0);                              \
        GLD16(buf[1], ap0 + (kc_) * 128 + 32);                             \
        GLD16(buf[2], ap0 + (kc_) * 128 + 64);                             \
        GLD16(buf[3], ap0 + (kc_) * 128 + 96);                             \
        GLD16(buf[4], ap1 + (kc_) * 128 + 0);                              \
        GLD16(buf[5], ap1 + (kc_) * 128 + 32);                             \
        GLD16(buf[6], ap1 + (kc_) * 128 + 64);                             \
        GLD16(buf[7], ap1 + (kc_) * 128 + 96);                             \
    } while (0)

#define CONSUME(buf, kc_) do {                                             \
        _Pragma("unroll")                                                  \
        for (int ks_ = 0; ks_ < 4; ++ks_) {                                \
            const int kb_ = (kc_) * 128 + ks_ * 32 + lk * 8;               \
            short8 bv0_ = *(const short8*)&Whs[lr][kb_];                   \
            short8 bv1_ = *(const short8*)&Whs[16 + lr][kb_];              \
            short8 a0_ = __builtin_bit_cast(short8, buf[ks_]);             \
            short8 a1_ = __builtin_bit_cast(short8, buf[4 + ks_]);         \
            acc00 = mfma16(a0_, bv0_, acc00);                              \
            acc01 = mfma16(a0_, bv1_, acc01);                              \
            acc10 = mfma16(a1_, bv0_, acc10);                              \
            acc11 = mfma16(a1_, bv1_, acc11);                              \
        }                                                                  \
    } while (0)

    for (int s = 0; s < nsteps; ++s) {
        const int t = t0 + s;
        const unsigned short* hsrc = hbuf + (size_t)(t & 1) * BH;
        const unsigned short* ap0 = hsrc + (size_t)rowA0 * Hsz + lk * 8;
        const unsigned short* ap1 = hsrc + (size_t)rowA1 * Hsz + lk * 8;

        f32x4 acc00 = {}, acc01 = {}, acc10 = {}, acc11 = {};
        uint4v A[8], Bb[8];
        // wait-then-consume pipeline; every WAITVM(8) has >=8 younger vmem ops
        ISSUE_CHUNK(A, 0);  ISSUE_CHUNK(Bb, 1);
        WAITVM(8);  CONSUME(A, 0);   ISSUE_CHUNK(A, 2);
        WAITVM(8);  CONSUME(Bb, 1);  ISSUE_CHUNK(Bb, 3);
        WAITVM(8);  CONSUME(A, 2);   ISSUE_CHUNK(A, 4);
        WAITVM(8);  CONSUME(Bb, 3);  ISSUE_CHUNK(Bb, 5);
        WAITVM(8);  CONSUME(A, 4);   ISSUE_CHUNK(A, 6);
        WAITVM(8);  CONSUME(Bb, 5);  ISSUE_CHUNK(Bb, 7);
        WAITVM(8);  CONSUME(A, 6);
        WAITVM(0);  CONSUME(Bb, 7);

        // gates fully in registers; xp addend from LDS; partner lane lr+8 holds f/o partials
        #pragma unroll
        for (int mi = 0; mi < 2; ++mi) {
            f32x4 aIF = mi ? acc10 : acc00;
            f32x4 aGO = mi ? acc11 : acc01;
            #pragma unroll
            for (int r = 0; r < 4; ++r) {
                float zfp = __shfl_xor(aIF[r], 8);
                float zop = __shfl_xor(aGO[r], 8);
                if (own) {
                    int b = 32 * w + mi * 16 + 4 * lk + r;
                    const unsigned short* xb = &xps[b * 32 + jj];
                    float zi = aIF[r] + bf2f(xb[0]);
                    float zf = zfp    + bf2f(xb[8]);
                    float zg = aGO[r] + bf2f(xb[16]);
                    float zo = zop    + bf2f(xb[24]);
                    float it = 1.f / (1.f + __expf(-zi));
                    float ft = 1.f / (1.f + __expf(-zf));
                    float gt = tanhf(zg);
                    float ot = 1.f / (1.f + __expf(-zo));
                    float c = ft * creg[mi][r] + it * gt;
                    creg[mi][r] = c;
                    float h = ot * tanhf(c);
                    if (lenr[mi][r] == t + 1) outh[(size_t)b * Hsz + j0 + jj] = h;
                    unsigned hv = f2bf(h);
                    unsigned short* hd = hbuf + (size_t)((t + 1) & 1) * BH
                                       + (size_t)b * Hsz + j0 + jj;
                    STORE_H16(hd, hv);
                }
            }
        }

        __syncthreads();   // h stores drained (vmcnt 0); xps reads for step s done

        // stage next step's xp slice into LDS (overlaps barrier wait; LDS survives fence)
        {
            int sn = (s + 1 < nsteps) ? s + 1 : s;
            const short8* sp = (const short8*)(xp + ((size_t)sn * NB + blk) * ((size_t)Bsz * 32));
            short8 v0 = sp[tid * 2], v1 = sp[tid * 2 + 1];
            *(short8*)&xps[tid * 16] = v0;
            *(short8*)&xps[tid * 16 + 8] = v1;
        }

        // ---- grid barrier (single u64 {gen,count}, relaxed) ----
        if (tid == 0) {
            unsigned long long v = __hip_atomic_load(bar, __ATOMIC_RELAXED, __HIP_MEMORY_SCOPE_AGENT);
            unsigned gen = (unsigned)(v >> 32);
            unsigned long long old = __hip_atomic_fetch_add(bar, 1ull, __ATOMIC_RELAXED, __HIP_MEMORY_SCOPE_AGENT);
            if ((unsigned)old == NB - 1u) {
                __hip_atomic_fetch_add(bar, (1ull << 32) - (unsigned long long)NB,
                                       __ATOMIC_RELAXED, __HIP_MEMORY_SCOPE_AGENT);
            } else {
                unsigned long long cur;
                do {
                    __builtin_amdgcn_s_sleep(2);
                    cur = __hip_atomic_load(bar, __ATOMIC_RELAXED, __HIP_MEMORY_SCOPE_AGENT);
                } while ((unsigned)(cur >> 32) == gen);
            }
        }
        __syncthreads();
        // agent acquire: invalidate L1/L2 so next step's cached h loads are fresh
        __builtin_amdgcn_fence(__ATOMIC_ACQUIRE, "agent");
        __builtin_amdgcn_sched_barrier(0);
    }

    #pragma unroll
    for (int mi = 0; mi < 2; ++mi)
        #pragma unroll
        for (int r = 0; r < 4; ++r)
            if (own) {
                int b = 32 * w + mi * 16 + 4 * lk + r;
                cbuf[(size_t)b * Hsz + j0 + jj] = creg[mi][r];
            }
#undef ISSUE_CHUNK
#undef CONSUME
}

// ---------------- final fc ----------------
__global__ __launch_bounds__(64) void k_fc(const float* __restrict__ outh,
                                           const float* __restrict__ fc_w,
                                           const float* __restrict__ fc_b,
                                           float* __restrict__ out) {
    int b = blockIdx.x, l = threadIdx.x;
    float s = 0.f;
    for (int k = l; k < Hsz; k += 64) s += outh[(size_t)b * Hsz + k] * fc_w[k];
    #pragma unroll
    for (int o = 32; o > 0; o >>= 1) s += __shfl_down(s, o);
    if (l == 0) out[b] = s + fc_b[0];
}

extern "C" void kernel_launch(void* const* d_in, const int* in_sizes, int n_in,
                              void* d_out, int out_size, void* d_ws, size_t ws_size,
                              hipStream_t stream) {
    const int* x       = (const int*)d_in[0];
    const int* lengths = (const int*)d_in[1];
    const float* emb   = (const float*)d_in[2];
    const float* W_ii  = (const float*)d_in[3];
    const float* W_hi  = (const float*)d_in[4];
    const float* b_i   = (const float*)d_in[5];
    const float* W_if  = (const float*)d_in[6];
    const float* W_hf  = (const float*)d_in[7];
    const float* b_f   = (const float*)d_in[8];
    const float* W_ig  = (const float*)d_in[9];
    const float* W_hg  = (const float*)d_in[10];
    const float* b_g   = (const float*)d_in[11];
    const float* W_io  = (const float*)d_in[12];
    const float* W_ho  = (const float*)d_in[13];
    const float* b_o   = (const float*)d_in[14];
    const float* fc_w  = (const float*)d_in[15];
    const float* fc_b  = (const float*)d_in[16];
    float* out = (float*)d_out;

    char* ws = (char*)d_ws;
    size_t off = 0;
    auto take = [&](size_t bytes) { size_t o = off; off += (bytes + 255) & ~(size_t)255; return o; };
    unsigned long long* bar = (unsigned long long*)(ws + take(256));
    unsigned short* hbuf  = (unsigned short*)(ws + take((size_t)2 * Bsz * Hsz * 2));
    float* cbuf           = (float*)(ws + take((size_t)Bsz * Hsz * 4));
    float* outh           = (float*)(ws + take((size_t)Bsz * Hsz * 4));
    float* b4             = (float*)(ws + take((size_t)G4H * 4));
    unsigned short* Wi16  = (unsigned short*)(ws + take((size_t)G4H * Esz * 2));
    unsigned short* Wh16  = (unsigned short*)(ws + take((size_t)G4H * Hsz * 2));
    unsigned short* emb16 = (unsigned short*)(ws + take((size_t)Vsz * Esz * 2));
    size_t fixed = off;

    int TC = 128;
    while (TC > 1 && fixed + (size_t)TC * Bsz * G4H * 2 > ws_size) TC >>= 1;
    unsigned short* xp = (unsigned short*)(ws + take((size_t)TC * Bsz * G4H * 2));

    k_prep_emb<<<(Vsz * Esz + 255) / 256, 256, 0, stream>>>(emb, emb16);
    k_prep_w<<<(4 * Hsz * Esz + 255) / 256, 256, 0, stream>>>(W_ii, W_if, W_ig, W_io, Esz, Wi16);
    k_prep_w<<<(4 * Hsz * Hsz + 255) / 256, 256, 0, stream>>>(W_hi, W_hf, W_hg, W_ho, Hsz, Wh16);
    k_prep_misc<<<(2 * Bsz * Hsz + 255) / 256, 256, 0, stream>>>(b_i, b_f, b_g, b_o, b4, hbuf, cbuf, outh, bar);

    for (int c = 0; c < Tsz / TC; ++c) {
        dim3 g(TC, 32);
        xp_gemm<<<g, 256, 0, stream>>>(emb16, Wi16, b4, x, xp, c * TC);
        lstm_steps<<<NB, 256, 0, stream>>>(Wh16, xp, lengths, hbuf, cbuf, outh, bar, c * TC, TC);
    }
    k_fc<<<Bsz, 64, 0, stream>>>(outh, fc_w, fc_b, out);
}

// Round 5
// 8636.644 us; speedup vs baseline: 1.6761x; 1.2479x over previous
//
#include <hip/hip_runtime.h>
#include <math.h>

#define Bsz 128
#define Tsz 512
#define Esz 512
#define Hsz 1024
#define G4H 4096
#define Vsz 32000
#define NB  128          // lstm blocks
#define BH  (Bsz * Hsz)

typedef __attribute__((ext_vector_type(8))) short short8;
typedef __attribute__((ext_vector_type(8))) __bf16 bf16x8;
typedef __attribute__((ext_vector_type(4))) float f32x4;
typedef __attribute__((ext_vector_type(4))) unsigned int uint4v;

__device__ inline unsigned short f2bf(float f) {
    unsigned u = __float_as_uint(f);
    u += 0x7fffu + ((u >> 16) & 1u);   // RTNE
    return (unsigned short)(u >> 16);
}
__device__ inline float bf2f(unsigned short s) {
    return __uint_as_float(((unsigned)s) << 16);
}
__device__ inline f32x4 mfma16(short8 a, short8 b, f32x4 c) {
    return __builtin_amdgcn_mfma_f32_16x16x32_bf16(
        __builtin_bit_cast(bf16x8, a), __builtin_bit_cast(bf16x8, b), c, 0, 0, 0);
}

// coherent async 16B load: sc0 sc1 bypasses L1/L2, reads the MALL (coherent point).
// early-clobber so dst never aliases addr regs.
#define GLD16C(dst, p)                                                     \
    asm volatile("global_load_dwordx4 %0, %1, off sc0 sc1" : "=&v"(dst) : "v"(p))

#define WAITVM(n)                                                          \
    do { asm volatile("s_waitcnt vmcnt(" #n ")" ::: "memory");             \
         __builtin_amdgcn_sched_barrier(0); } while (0)

// device-coherent write-through store of one bf16 (low 16 bits of v)
#define STORE_H16(p, v)                                                    \
    asm volatile("global_store_short %0, %1, off sc0 sc1" ::"v"(p), "v"(v) : "memory")

// ---------------- prep kernels ----------------
__global__ void k_prep_emb(const float* __restrict__ emb, unsigned short* __restrict__ dst) {
    size_t i = (size_t)blockIdx.x * 256 + threadIdx.x;
    if (i < (size_t)Vsz * Esz) dst[i] = f2bf(i < Esz ? 0.f : emb[i]);  // row 0 = PAD -> 0
}

__global__ void k_prep_w(const float* __restrict__ wi, const float* __restrict__ wf,
                         const float* __restrict__ wg, const float* __restrict__ wo,
                         int ncols, unsigned short* __restrict__ dst) {
    size_t i = (size_t)blockIdx.x * 256 + threadIdx.x;
    size_t per = (size_t)Hsz * ncols;
    if (i < 4 * per) {
        int g = (int)(i / per);
        size_t rem = i - (size_t)g * per;
        const float* src = g == 0 ? wi : g == 1 ? wf : g == 2 ? wg : wo;
        dst[i] = f2bf(src[rem]);
    }
}

__global__ void k_prep_misc(const float* __restrict__ bi, const float* __restrict__ bff,
                            const float* __restrict__ bg, const float* __restrict__ bo,
                            float* __restrict__ b4, unsigned short* __restrict__ hbuf,
                            float* __restrict__ cbuf, float* __restrict__ outh,
                            unsigned long long* __restrict__ bar) {
    int i = blockIdx.x * 256 + threadIdx.x;
    if (i < G4H) {
        const float* src = i < Hsz ? bi : i < 2 * Hsz ? bff : i < 3 * Hsz ? bg : bo;
        b4[i] = src[i & (Hsz - 1)];
    }
    if (i < 2 * Bsz * Hsz) hbuf[i] = 0;
    if (i < Bsz * Hsz) { cbuf[i] = 0.f; outh[i] = 0.f; }
    if (i == 0) *bar = 0ull;
}

// ---------------- xp = emb[x] @ Wi^T + b ----------------
// Output layout: xp[t'][blk][b][gate][jj]  -> each lstm block's slice contiguous 8 KB.
__global__ __launch_bounds__(256, 2) void xp_gemm(
    const unsigned short* __restrict__ emb16, const unsigned short* __restrict__ Wi16,
    const float* __restrict__ b4, const int* __restrict__ x,
    unsigned short* __restrict__ xp, int t_base)
{
    const int tp = blockIdx.x;
    const int n0 = blockIdx.y * 128;
    const int tid = threadIdx.x;
    const int w = tid >> 6, l = tid & 63;
    const int wm = w >> 1, wn = w & 1;
    const int lr = l & 15, lk = l >> 4;

    const unsigned short* arow[4];
    #pragma unroll
    for (int mt = 0; mt < 4; ++mt) {
        int b = wm * 64 + mt * 16 + lr;
        int xv = x[b * Tsz + t_base + tp];
        arow[mt] = emb16 + (size_t)xv * Esz + lk * 8;
    }
    const unsigned short* brow[4];
    #pragma unroll
    for (int nt = 0; nt < 4; ++nt) {
        int n = n0 + wn * 64 + nt * 16 + lr;
        brow[nt] = Wi16 + (size_t)n * Esz + lk * 8;
    }
    f32x4 acc[4][4] = {};
    #pragma unroll 2
    for (int k0 = 0; k0 < Esz; k0 += 32) {
        short8 av[4], bv[4];
        #pragma unroll
        for (int mt = 0; mt < 4; ++mt) av[mt] = *(const short8*)(arow[mt] + k0);
        #pragma unroll
        for (int nt = 0; nt < 4; ++nt) bv[nt] = *(const short8*)(brow[nt] + k0);
        #pragma unroll
        for (int mt = 0; mt < 4; ++mt)
            #pragma unroll
            for (int nt = 0; nt < 4; ++nt)
                acc[mt][nt] = mfma16(av[mt], bv[nt], acc[mt][nt]);
    }
    #pragma unroll
    for (int nt = 0; nt < 4; ++nt) {
        int n = n0 + wn * 64 + nt * 16 + lr;
        float bias = b4[n];
        int g = n >> 10, j = n & 1023;
        int bk = j >> 3, jj = j & 7;
        #pragma unroll
        for (int mt = 0; mt < 4; ++mt) {
            #pragma unroll
            for (int r = 0; r < 4; ++r) {
                int b = wm * 64 + mt * 16 + lk * 4 + r;
                xp[(((size_t)tp * NB + bk) * Bsz + b) * 32 + g * 8 + jj] =
                    f2bf(acc[mt][nt][r] + bias);
            }
        }
    }
}

// ---------------- fused recurrence ----------------
// 128 blocks x 4 waves. Block owns 8 h-cols (j0) x 4 gates = 32 Wh rows in LDS.
// h exchange is MALL-coherent: sc0sc1 write-through stores + sc0sc1 loads.
// NO per-step cache fence -> L2 keeps xp/Wh/lengths hot across steps.
__global__ __launch_bounds__(256, 1) void lstm_steps(
    const unsigned short* __restrict__ Wh16,
    const unsigned short* __restrict__ xp,    // [T'][NB][B][4][8] bf16
    const int* __restrict__ lengths,
    unsigned short* __restrict__ hbuf,        // [2][B][H] bf16 double buffer
    float* __restrict__ cbuf,
    float* __restrict__ outh,
    unsigned long long* __restrict__ bar,     // packed {gen:32, count:32}
    int t0, int nsteps)
{
    __shared__ unsigned short Whs[32][1032];   // 66 KB
    __shared__ unsigned short xps[Bsz * 32];   // 8 KB: [b][gate][jj] for current step
    const int tid = threadIdx.x;
    const int blk = blockIdx.x;
    const int j0 = blk * 8;

    // stage Wh slice: local row n -> gate n>>3, col j0+(n&7)
    for (int idx = tid; idx < 32 * 128; idx += 256) {
        int n = idx >> 7, ck = idx & 127;
        int grow = (n >> 3) * Hsz + j0 + (n & 7);
        *(short8*)&Whs[n][ck * 8] = *(const short8*)(Wh16 + (size_t)grow * Hsz + ck * 8);
    }

    const int w = tid >> 6, l = tid & 63, lr = l & 15, lk = l >> 4;
    const bool own = (lr < 8);
    const int jj = lr & 7;

    int lenr[2][4];
    float creg[2][4];
    #pragma unroll
    for (int mi = 0; mi < 2; ++mi)
        #pragma unroll
        for (int r = 0; r < 4; ++r) {
            int b = 32 * w + mi * 16 + 4 * lk + r;
            lenr[mi][r] = own ? lengths[b] : 0;
            creg[mi][r] = own ? cbuf[(size_t)b * Hsz + j0 + jj] : 0.f;
        }

    // prologue: stage xp slice for s=0
    {
        const short8* sp = (const short8*)(xp + ((size_t)0 * NB + blk) * ((size_t)Bsz * 32));
        short8 v0 = sp[tid * 2], v1 = sp[tid * 2 + 1];
        *(short8*)&xps[tid * 16] = v0;
        *(short8*)&xps[tid * 16 + 8] = v1;
    }
    __syncthreads();

    const int rowA0 = 32 * w + lr;
    const int rowA1 = rowA0 + 16;

#define ISSUE_CHUNK(buf, kc_) do {                                         \
        GLD16C(buf[0], ap0 + (kc_) * 128 + 0);                             \
        GLD16C(buf[1], ap0 + (kc_) * 128 + 32);                            \
        GLD16C(buf[2], ap0 + (kc_) * 128 + 64);                            \
        GLD16C(buf[3], ap0 + (kc_) * 128 + 96);                            \
        GLD16C(buf[4], ap1 + (kc_) * 128 + 0);                             \
        GLD16C(buf[5], ap1 + (kc_) * 128 + 32);                            \
        GLD16C(buf[6], ap1 + (kc_) * 128 + 64);                            \
        GLD16C(buf[7], ap1 + (kc_) * 128 + 96);                            \
    } while (0)

#define CONSUME(buf, kc_) do {                                             \
        _Pragma("unroll")                                                  \
        for (int ks_ = 0; ks_ < 4; ++ks_) {                                \
            const int kb_ = (kc_) * 128 + ks_ * 32 + lk * 8;               \
            short8 bv0_ = *(const short8*)&Whs[lr][kb_];                   \
            short8 bv1_ = *(const short8*)&Whs[16 + lr][kb_];              \
            short8 a0_ = __builtin_bit_cast(short8, buf[ks_]);             \
            short8 a1_ = __builtin_bit_cast(short8, buf[4 + ks_]);         \
            acc00 = mfma16(a0_, bv0_, acc00);                              \
            acc01 = mfma16(a0_, bv1_, acc01);                              \
            acc10 = mfma16(a1_, bv0_, acc10);                              \
            acc11 = mfma16(a1_, bv1_, acc11);                              \
        }                                                                  \
    } while (0)

    for (int s = 0; s < nsteps; ++s) {
        const int t = t0 + s;
        const unsigned short* hsrc = hbuf + (size_t)(t & 1) * BH;
        const unsigned short* ap0 = hsrc + (size_t)rowA0 * Hsz + lk * 8;
        const unsigned short* ap1 = hsrc + (size_t)rowA1 * Hsz + lk * 8;

        f32x4 acc00 = {}, acc01 = {}, acc10 = {}, acc11 = {};
        uint4v A[8], Bb[8];
        // wait-then-consume pipeline; every WAITVM(8) has >=8 younger vmem ops
        ISSUE_CHUNK(A, 0);  ISSUE_CHUNK(Bb, 1);
        WAITVM(8);  CONSUME(A, 0);   ISSUE_CHUNK(A, 2);
        WAITVM(8);  CONSUME(Bb, 1);  ISSUE_CHUNK(Bb, 3);
        WAITVM(8);  CONSUME(A, 2);   ISSUE_CHUNK(A, 4);
        WAITVM(8);  CONSUME(Bb, 3);  ISSUE_CHUNK(Bb, 5);
        WAITVM(8);  CONSUME(A, 4);   ISSUE_CHUNK(A, 6);
        WAITVM(8);  CONSUME(Bb, 5);  ISSUE_CHUNK(Bb, 7);
        WAITVM(8);  CONSUME(A, 6);
        WAITVM(0);  CONSUME(Bb, 7);

        // gates fully in registers; xp addend from LDS; partner lane lr+8 holds f/o partials
        #pragma unroll
        for (int mi = 0; mi < 2; ++mi) {
            f32x4 aIF = mi ? acc10 : acc00;
            f32x4 aGO = mi ? acc11 : acc01;
            #pragma unroll
            for (int r = 0; r < 4; ++r) {
                float zfp = __shfl_xor(aIF[r], 8);
                float zop = __shfl_xor(aGO[r], 8);
                if (own) {
                    int b = 32 * w + mi * 16 + 4 * lk + r;
                    const unsigned short* xb = &xps[b * 32 + jj];
                    float zi = aIF[r] + bf2f(xb[0]);
                    float zf = zfp    + bf2f(xb[8]);
                    float zg = aGO[r] + bf2f(xb[16]);
                    float zo = zop    + bf2f(xb[24]);
                    float it = 1.f / (1.f + __expf(-zi));
                    float ft = 1.f / (1.f + __expf(-zf));
                    float gt = tanhf(zg);
                    float ot = 1.f / (1.f + __expf(-zo));
                    float c = ft * creg[mi][r] + it * gt;
                    creg[mi][r] = c;
                    float h = ot * tanhf(c);
                    if (lenr[mi][r] == t + 1) outh[(size_t)b * Hsz + j0 + jj] = h;
                    unsigned hv = f2bf(h);
                    unsigned short* hd = hbuf + (size_t)((t + 1) & 1) * BH
                                       + (size_t)b * Hsz + j0 + jj;
                    STORE_H16(hd, hv);
                }
            }
        }

        __syncthreads();   // waits vmcnt(0): sc0sc1 h stores ACKed at the coherent point

        // stage next step's xp slice into LDS (overlaps the barrier wait)
        {
            int sn = (s + 1 < nsteps) ? s + 1 : s;
            const short8* sp = (const short8*)(xp + ((size_t)sn * NB + blk) * ((size_t)Bsz * 32));
            short8 v0 = sp[tid * 2], v1 = sp[tid * 2 + 1];
            *(short8*)&xps[tid * 16] = v0;
            *(short8*)&xps[tid * 16 + 8] = v1;
        }

        // ---- grid barrier (single u64 {gen,count}, relaxed) ----
        if (tid == 0) {
            unsigned long long v = __hip_atomic_load(bar, __ATOMIC_RELAXED, __HIP_MEMORY_SCOPE_AGENT);
            unsigned gen = (unsigned)(v >> 32);
            unsigned long long old = __hip_atomic_fetch_add(bar, 1ull, __ATOMIC_RELAXED, __HIP_MEMORY_SCOPE_AGENT);
            if ((unsigned)old == NB - 1u) {
                __hip_atomic_fetch_add(bar, (1ull << 32) - (unsigned long long)NB,
                                       __ATOMIC_RELAXED, __HIP_MEMORY_SCOPE_AGENT);
            } else {
                unsigned long long cur;
                do {
                    __builtin_amdgcn_s_sleep(1);
                    cur = __hip_atomic_load(bar, __ATOMIC_RELAXED, __HIP_MEMORY_SCOPE_AGENT);
                } while ((unsigned)(cur >> 32) == gen);
            }
        }
        __syncthreads();
        __builtin_amdgcn_sched_barrier(0);   // keep next-step loads below the barrier
    }

    #pragma unroll
    for (int mi = 0; mi < 2; ++mi)
        #pragma unroll
        for (int r = 0; r < 4; ++r)
            if (own) {
                int b = 32 * w + mi * 16 + 4 * lk + r;
                cbuf[(size_t)b * Hsz + j0 + jj] = creg[mi][r];
            }
#undef ISSUE_CHUNK
#undef CONSUME
}

// ---------------- final fc ----------------
__global__ __launch_bounds__(64) void k_fc(const float* __restrict__ outh,
                                           const float* __restrict__ fc_w,
                                           const float* __restrict__ fc_b,
                                           float* __restrict__ out) {
    int b = blockIdx.x, l = threadIdx.x;
    float s = 0.f;
    for (int k = l; k < Hsz; k += 64) s += outh[(size_t)b * Hsz + k] * fc_w[k];
    #pragma unroll
    for (int o = 32; o > 0; o >>= 1) s += __shfl_down(s, o);
    if (l == 0) out[b] = s + fc_b[0];
}

extern "C" void kernel_launch(void* const* d_in, const int* in_sizes, int n_in,
                              void* d_out, int out_size, void* d_ws, size_t ws_size,
                              hipStream_t stream) {
    const int* x       = (const int*)d_in[0];
    const int* lengths = (const int*)d_in[1];
    const float* emb   = (const float*)d_in[2];
    const float* W_ii  = (const float*)d_in[3];
    const float* W_hi  = (const float*)d_in[4];
    const float* b_i   = (const float*)d_in[5];
    const float* W_if  = (const float*)d_in[6];
    const float* W_hf  = (const float*)d_in[7];
    const float* b_f   = (const float*)d_in[8];
    const float* W_ig  = (const float*)d_in[9];
    const float* W_hg  = (const float*)d_in[10];
    const float* b_g   = (const float*)d_in[11];
    const float* W_io  = (const float*)d_in[12];
    const float* W_ho  = (const float*)d_in[13];
    const float* b_o   = (const float*)d_in[14];
    const float* fc_w  = (const float*)d_in[15];
    const float* fc_b  = (const float*)d_in[16];
    float* out = (float*)d_out;

    char* ws = (char*)d_ws;
    size_t off = 0;
    auto take = [&](size_t bytes) { size_t o = off; off += (bytes + 255) & ~(size_t)255; return o; };
    unsigned long long* bar = (unsigned long long*)(ws + take(256));
    unsigned short* hbuf  = (unsigned short*)(ws + take((size_t)2 * Bsz * Hsz * 2));
    float* cbuf           = (float*)(ws + take((size_t)Bsz * Hsz * 4));
    float* outh           = (float*)(ws + take((size_t)Bsz * Hsz * 4));
    float* b4             = (float*)(ws + take((size_t)G4H * 4));
    unsigned short* Wi16  = (unsigned short*)(ws + take((size_t)G4H * Esz * 2));
    unsigned short* Wh16  = (unsigned short*)(ws + take((size_t)G4H * Hsz * 2));
    unsigned short* emb16 = (unsigned short*)(ws + take((size_t)Vsz * Esz * 2));
    size_t fixed = off;

    int TC = 128;
    while (TC > 1 && fixed + (size_t)TC * Bsz * G4H * 2 > ws_size) TC >>= 1;
    unsigned short* xp = (unsigned short*)(ws + take((size_t)TC * Bsz * G4H * 2));

    k_prep_emb<<<(Vsz * Esz + 255) / 256, 256, 0, stream>>>(emb, emb16);
    k_prep_w<<<(4 * Hsz * Esz + 255) / 256, 256, 0, stream>>>(W_ii, W_if, W_ig, W_io, Esz, Wi16);
    k_prep_w<<<(4 * Hsz * Hsz + 255) / 256, 256, 0, stream>>>(W_hi, W_hf, W_hg, W_ho, Hsz, Wh16);
    k_prep_misc<<<(2 * Bsz * Hsz + 255) / 256, 256, 0, stream>>>(b_i, b_f, b_g, b_o, b4, hbuf, cbuf, outh, bar);

    for (int c = 0; c < Tsz / TC; ++c) {
        dim3 g(TC, 32);
        xp_gemm<<<g, 256, 0, stream>>>(emb16, Wi16, b4, x, xp, c * TC);
        lstm_steps<<<NB, 256, 0, stream>>>(Wh16, xp, lengths, hbuf, cbuf, outh, bar, c * TC, TC);
    }
    k_fc<<<Bsz, 64, 0, stream>>>(outh, fc_w, fc_b, out);
}

// Round 7
// 6328.305 us; speedup vs baseline: 2.2875x; 1.3648x over previous
//
#include <hip/hip_runtime.h>
#include <math.h>

#define Bsz 128
#define Tsz 512
#define Esz 512
#define Hsz 1024
#define G4H 4096
#define Vsz 32000
#define NB  128          // lstm blocks
#define BH  (Bsz * Hsz)

typedef __attribute__((ext_vector_type(8))) short short8;
typedef __attribute__((ext_vector_type(8))) __bf16 bf16x8;
typedef __attribute__((ext_vector_type(4))) float f32x4;
typedef __attribute__((ext_vector_type(4))) unsigned int uint4v;

__device__ inline unsigned short f2bf(float f) {
    unsigned u = __float_as_uint(f);
    u += 0x7fffu + ((u >> 16) & 1u);   // RTNE
    return (unsigned short)(u >> 16);
}
__device__ inline float bf2f(unsigned short s) {
    return __uint_as_float(((unsigned)s) << 16);
}
__device__ inline f32x4 mfma16(short8 a, short8 b, f32x4 c) {
    return __builtin_amdgcn_mfma_f32_16x16x32_bf16(
        __builtin_bit_cast(bf16x8, a), __builtin_bit_cast(bf16x8, b), c, 0, 0, 0);
}

// async 16B loads; early-clobber so dst never aliases addr regs
#define GLD16P(dst, p)  asm volatile("global_load_dwordx4 %0, %1, off"         : "=&v"(dst) : "v"(p))
#define GLD16C(dst, p)  asm volatile("global_load_dwordx4 %0, %1, off sc0 sc1" : "=&v"(dst) : "v"(p))

#define WAITVM(n)                                                          \
    do { asm volatile("s_waitcnt vmcnt(" #n ")" ::: "memory");             \
         __builtin_amdgcn_sched_barrier(0); } while (0)

// ---------------- prep kernels ----------------
__global__ void k_prep_emb(const float* __restrict__ emb, unsigned short* __restrict__ dst) {
    size_t i = (size_t)blockIdx.x * 256 + threadIdx.x;
    if (i < (size_t)Vsz * Esz) dst[i] = f2bf(i < Esz ? 0.f : emb[i]);  // row 0 = PAD -> 0
}

__global__ void k_prep_w(const float* __restrict__ wi, const float* __restrict__ wf,
                         const float* __restrict__ wg, const float* __restrict__ wo,
                         int ncols, unsigned short* __restrict__ dst) {
    size_t i = (size_t)blockIdx.x * 256 + threadIdx.x;
    size_t per = (size_t)Hsz * ncols;
    if (i < 4 * per) {
        int g = (int)(i / per);
        size_t rem = i - (size_t)g * per;
        const float* src = g == 0 ? wi : g == 1 ? wf : g == 2 ? wg : wo;
        dst[i] = f2bf(src[rem]);
    }
}

__global__ void k_prep_misc(const float* __restrict__ bi, const float* __restrict__ bff,
                            const float* __restrict__ bg, const float* __restrict__ bo,
                            float* __restrict__ b4, unsigned short* __restrict__ ghbuf,
                            float* __restrict__ cbuf, float* __restrict__ outh,
                            unsigned long long* __restrict__ bar) {
    int i = blockIdx.x * 256 + threadIdx.x;
    if (i < G4H) {
        const float* src = i < Hsz ? bi : i < 2 * Hsz ? bff : i < 3 * Hsz ? bg : bo;
        b4[i] = src[i & (Hsz - 1)];
    }
    if (i < 2 * BH) ghbuf[i] = 0;
    if (i < BH) { cbuf[i] = 0.f; outh[i] = 0.f; }
    if (i == 0) *bar = 0ull;
}

// ---------------- xp = emb[x] @ Wi^T + b  (verified; layout [t'][blk][b][gate][8]) ----------------
__global__ __launch_bounds__(256, 2) void xp_gemm(
    const unsigned short* __restrict__ emb16, const unsigned short* __restrict__ Wi16,
    const float* __restrict__ b4, const int* __restrict__ x,
    unsigned short* __restrict__ xp, int t_base)
{
    const int tp = blockIdx.x;
    const int n0 = blockIdx.y * 128;
    const int tid = threadIdx.x;
    const int w = tid >> 6, l = tid & 63;
    const int wm = w >> 1, wn = w & 1;
    const int lr = l & 15, lk = l >> 4;

    const unsigned short* arow[4];
    #pragma unroll
    for (int mt = 0; mt < 4; ++mt) {
        int b = wm * 64 + mt * 16 + lr;
        int xv = x[b * Tsz + t_base + tp];
        arow[mt] = emb16 + (size_t)xv * Esz + lk * 8;
    }
    const unsigned short* brow[4];
    #pragma unroll
    for (int nt = 0; nt < 4; ++nt) {
        int n = n0 + wn * 64 + nt * 16 + lr;
        brow[nt] = Wi16 + (size_t)n * Esz + lk * 8;
    }
    f32x4 acc[4][4] = {};
    #pragma unroll 2
    for (int k0 = 0; k0 < Esz; k0 += 32) {
        short8 av[4], bv[4];
        #pragma unroll
        for (int mt = 0; mt < 4; ++mt) av[mt] = *(const short8*)(arow[mt] + k0);
        #pragma unroll
        for (int nt = 0; nt < 4; ++nt) bv[nt] = *(const short8*)(brow[nt] + k0);
        #pragma unroll
        for (int mt = 0; mt < 4; ++mt)
            #pragma unroll
            for (int nt = 0; nt < 4; ++nt)
                acc[mt][nt] = mfma16(av[mt], bv[nt], acc[mt][nt]);
    }
    #pragma unroll
    for (int nt = 0; nt < 4; ++nt) {
        int n = n0 + wn * 64 + nt * 16 + lr;
        float bias = b4[n];
        int g = n >> 10, j = n & 1023;
        int bk = j >> 3, jj = j & 7;
        #pragma unroll
        for (int mt = 0; mt < 4; ++mt) {
            #pragma unroll
            for (int r = 0; r < 4; ++r) {
                int b = wm * 64 + mt * 16 + lk * 4 + r;
                xp[(((size_t)tp * NB + bk) * Bsz + b) * 32 + g * 8 + jj] =
                    f2bf(acc[mt][nt][r] + bias);
            }
        }
    }
}

// ---------------- fused recurrence ----------------
// h layout: ghbuf[2][slab=128][b=128][8] bf16, slab = k/8. MALL-coherent exchange:
// sc0sc1 write-through stores (one contiguous 2KB slab burst per block, staged in LDS)
// + sc0sc1 loads (wave instruction = 4 x 256B fully-used runs). No cache fences.
__global__ __launch_bounds__(256, 1) void lstm_steps(
    const unsigned short* __restrict__ Wh16,
    const unsigned short* __restrict__ xp,    // [T'][NB][B][4][8] bf16
    const int* __restrict__ lengths,
    unsigned short* __restrict__ ghbuf,       // [2][128][128][8] bf16 double buffer
    float* __restrict__ cbuf,
    float* __restrict__ outh,
    unsigned long long* __restrict__ bar,     // packed {gen:32, count:32}
    int t0, int nsteps)
{
    __shared__ unsigned short Whs[32][1032];   // 66 KB
    __shared__ unsigned short xps[Bsz * 32];   // 8 KB: [b][gate][jj] for current step
    __shared__ unsigned short hls[Bsz * 8];    // 2 KB: this block's h slab
    const int tid = threadIdx.x;
    const int blk = blockIdx.x;
    const int j0 = blk * 8;

    // stage Wh slice: local row n -> gate n>>3, col j0+(n&7)
    for (int idx = tid; idx < 32 * 128; idx += 256) {
        int n = idx >> 7, ck = idx & 127;
        int grow = (n >> 3) * Hsz + j0 + (n & 7);
        *(short8*)&Whs[n][ck * 8] = *(const short8*)(Wh16 + (size_t)grow * Hsz + ck * 8);
    }

    const int w = tid >> 6, l = tid & 63, lr = l & 15, lk = l >> 4;
    const bool own = (lr < 8);
    const int jj = lr & 7;

    int lenr[2][4];
    float creg[2][4];
    #pragma unroll
    for (int mi = 0; mi < 2; ++mi)
        #pragma unroll
        for (int r = 0; r < 4; ++r) {
            int b = 32 * w + mi * 16 + 4 * lk + r;
            lenr[mi][r] = own ? lengths[b] : 0;
            creg[mi][r] = own ? cbuf[(size_t)b * Hsz + j0 + jj] : 0.f;
        }

    // prologue: stage xp slice for s=0
    {
        const short8* sp = (const short8*)(xp + ((size_t)0 * NB + blk) * ((size_t)Bsz * 32));
        *(short8*)&xps[tid * 16]     = sp[tid * 2];
        *(short8*)&xps[tid * 16 + 8] = sp[tid * 2 + 1];
    }
    __syncthreads();

    const int rowA0 = 32 * w + lr;

    // A-load base: addr(b,k) shorts = (k>>3)*1024 + b*8 + (k&7); lane covers
    // k = kc*128 + ks*32 + lk*8 .. +7 -> slab = kc*16 + ks*4 + lk (lk folded into hb)
#define ISSUE_CHUNK(buf, kc_) do {                                         \
        GLD16C(buf[0], hb + ((kc_) * 16 + 0)  * 1024);                     \
        GLD16C(buf[1], hb + ((kc_) * 16 + 4)  * 1024);                     \
        GLD16C(buf[2], hb + ((kc_) * 16 + 8)  * 1024);                     \
        GLD16C(buf[3], hb + ((kc_) * 16 + 12) * 1024);                     \
        GLD16C(buf[4], hb + ((kc_) * 16 + 0)  * 1024 + 128);               \
        GLD16C(buf[5], hb + ((kc_) * 16 + 4)  * 1024 + 128);               \
        GLD16C(buf[6], hb + ((kc_) * 16 + 8)  * 1024 + 128);               \
        GLD16C(buf[7], hb + ((kc_) * 16 + 12) * 1024 + 128);               \
    } while (0)

#define CONSUME(buf, kc_) do {                                             \
        _Pragma("unroll")                                                  \
        for (int ks_ = 0; ks_ < 4; ++ks_) {                                \
            const int kb_ = (kc_) * 128 + ks_ * 32 + lk * 8;               \
            short8 bv0_ = *(const short8*)&Whs[lr][kb_];                   \
            short8 bv1_ = *(const short8*)&Whs[16 + lr][kb_];              \
            short8 a0_ = __builtin_bit_cast(short8, buf[ks_]);             \
            short8 a1_ = __builtin_bit_cast(short8, buf[4 + ks_]);         \
            acc00 = mfma16(a0_, bv0_, acc00);                              \
            acc01 = mfma16(a0_, bv1_, acc01);                              \
            acc10 = mfma16(a1_, bv0_, acc10);                              \
            acc11 = mfma16(a1_, bv1_, acc11);                              \
        }                                                                  \
    } while (0)

    for (int s = 0; s < nsteps; ++s) {
        const int t = t0 + s;
        const unsigned short* hb = ghbuf + (size_t)(t & 1) * BH + lk * 1024 + rowA0 * 8;
        int sn = (s + 1 < nsteps) ? s + 1 : s;
        const unsigned short* xpn = xp + ((size_t)sn * NB + blk) * ((size_t)Bsz * 32) + tid * 16;

        f32x4 acc00 = {}, acc01 = {}, acc10 = {}, acc11 = {};
        uint4v A[8], Bb[8], xr0, xr1;
        // wait-then-consume pipeline; xr prefetch issued last, drained before use
        ISSUE_CHUNK(A, 0);  ISSUE_CHUNK(Bb, 1);
        WAITVM(8);  CONSUME(A, 0);   ISSUE_CHUNK(A, 2);
        WAITVM(8);  CONSUME(Bb, 1);  ISSUE_CHUNK(Bb, 3);
        WAITVM(8);  CONSUME(A, 2);   ISSUE_CHUNK(A, 4);
        WAITVM(8);  CONSUME(Bb, 3);  ISSUE_CHUNK(Bb, 5);
        WAITVM(8);  CONSUME(A, 4);   ISSUE_CHUNK(A, 6);
        WAITVM(8);  CONSUME(Bb, 5);  ISSUE_CHUNK(Bb, 7);
        GLD16P(xr0, xpn); GLD16P(xr1, xpn + 8);
        WAITVM(10); CONSUME(A, 6);
        WAITVM(2);  CONSUME(Bb, 7);            // xr may still be in flight

        // gates fully in registers; xp addend from LDS; partner lane lr+8 holds f/o partials
        #pragma unroll
        for (int mi = 0; mi < 2; ++mi) {
            f32x4 aIF = mi ? acc10 : acc00;
            f32x4 aGO = mi ? acc11 : acc01;
            #pragma unroll
            for (int r = 0; r < 4; ++r) {
                float zfp = __shfl_xor(aIF[r], 8);
                float zop = __shfl_xor(aGO[r], 8);
                if (own) {
                    int b = 32 * w + mi * 16 + 4 * lk + r;
                    const unsigned short* xb = &xps[b * 32 + jj];
                    float zi = aIF[r] + bf2f(xb[0]);
                    float zf = zfp    + bf2f(xb[8]);
                    float zg = aGO[r] + bf2f(xb[16]);
                    float zo = zop    + bf2f(xb[24]);
                    float it = 1.f / (1.f + __expf(-zi));
                    float ft = 1.f / (1.f + __expf(-zf));
                    float gt = tanhf(zg);
                    float ot = 1.f / (1.f + __expf(-zo));
                    float c = ft * creg[mi][r] + it * gt;
                    creg[mi][r] = c;
                    float h = ot * tanhf(c);
                    if (lenr[mi][r] == t + 1) outh[(size_t)b * Hsz + j0 + jj] = h;
                    hls[b * 8 + jj] = f2bf(h);
                }
            }
        }
        __syncthreads();   // hls complete (all waves); xps reads for step s done

        // coalesced h slab store: one contiguous 2KB burst, write-through to MALL
        unsigned short* ghn = ghbuf + (size_t)((t + 1) & 1) * BH;
        if (tid < 128) {
            short8 hv8 = *(const short8*)&hls[tid * 8];
            unsigned short* hd = ghn + (size_t)blk * 1024 + tid * 8;
            asm volatile("global_store_dwordx4 %0, %1, off sc0 sc1"
                         :: "v"(hd), "v"(__builtin_bit_cast(uint4v, hv8)) : "memory");
        }

        // drain stores + xr, then restage xps from prefetched regs
        WAITVM(0);
        *(short8*)&xps[tid * 16]     = __builtin_bit_cast(short8, xr0);
        *(short8*)&xps[tid * 16 + 8] = __builtin_bit_cast(short8, xr1);

        // ---- grid barrier (single u64 {gen,count}, relaxed) ----
        if (tid == 0) {
            unsigned long long v = __hip_atomic_load(bar, __ATOMIC_RELAXED, __HIP_MEMORY_SCOPE_AGENT);
            unsigned gen = (unsigned)(v >> 32);
            unsigned long long old = __hip_atomic_fetch_add(bar, 1ull, __ATOMIC_RELAXED, __HIP_MEMORY_SCOPE_AGENT);
            if ((unsigned)old == NB - 1u) {
                __hip_atomic_fetch_add(bar, (1ull << 32) - (unsigned long long)NB,
                                       __ATOMIC_RELAXED, __HIP_MEMORY_SCOPE_AGENT);
            } else {
                unsigned long long cur;
                do {
                    __builtin_amdgcn_s_sleep(1);
                    cur = __hip_atomic_load(bar, __ATOMIC_RELAXED, __HIP_MEMORY_SCOPE_AGENT);
                } while ((unsigned)(cur >> 32) == gen);
            }
        }
        __syncthreads();
        __builtin_amdgcn_sched_barrier(0);   // keep next-step loads below the barrier
    }

    #pragma unroll
    for (int mi = 0; mi < 2; ++mi)
        #pragma unroll
        for (int r = 0; r < 4; ++r)
            if (own) {
                int b = 32 * w + mi * 16 + 4 * lk + r;
                cbuf[(size_t)b * Hsz + j0 + jj] = creg[mi][r];
            }
#undef ISSUE_CHUNK
#undef CONSUME
}

// ---------------- final fc ----------------
__global__ __launch_bounds__(64) void k_fc(const float* __restrict__ outh,
                                           const float* __restrict__ fc_w,
                                           const float* __restrict__ fc_b,
                                           float* __restrict__ out) {
    int b = blockIdx.x, l = threadIdx.x;
    float s = 0.f;
    for (int k = l; k < Hsz; k += 64) s += outh[(size_t)b * Hsz + k] * fc_w[k];
    #pragma unroll
    for (int o = 32; o > 0; o >>= 1) s += __shfl_down(s, o);
    if (l == 0) out[b] = s + fc_b[0];
}

extern "C" void kernel_launch(void* const* d_in, const int* in_sizes, int n_in,
                              void* d_out, int out_size, void* d_ws, size_t ws_size,
                              hipStream_t stream) {
    const int* x       = (const int*)d_in[0];
    const int* lengths = (const int*)d_in[1];
    const float* emb   = (const float*)d_in[2];
    const float* W_ii  = (const float*)d_in[3];
    const float* W_hi  = (const float*)d_in[4];
    const float* b_i   = (const float*)d_in[5];
    const float* W_if  = (const float*)d_in[6];
    const float* W_hf  = (const float*)d_in[7];
    const float* b_f   = (const float*)d_in[8];
    const float* W_ig  = (const float*)d_in[9];
    const float* W_hg  = (const float*)d_in[10];
    const float* b_g   = (const float*)d_in[11];
    const float* W_io  = (const float*)d_in[12];
    const float* W_ho  = (const float*)d_in[13];
    const float* b_o   = (const float*)d_in[14];
    const float* fc_w  = (const float*)d_in[15];
    const float* fc_b  = (const float*)d_in[16];
    float* out = (float*)d_out;

    char* ws = (char*)d_ws;
    size_t off = 0;
    auto take = [&](size_t bytes) { size_t o = off; off += (bytes + 255) & ~(size_t)255; return o; };
    unsigned long long* bar = (unsigned long long*)(ws + take(256));
    unsigned short* ghbuf = (unsigned short*)(ws + take((size_t)2 * BH * 2));
    float* cbuf           = (float*)(ws + take((size_t)BH * 4));
    float* outh           = (float*)(ws + take((size_t)BH * 4));
    float* b4             = (float*)(ws + take((size_t)G4H * 4));
    unsigned short* Wi16  = (unsigned short*)(ws + take((size_t)G4H * Esz * 2));
    unsigned short* Wh16  = (unsigned short*)(ws + take((size_t)G4H * Hsz * 2));
    unsigned short* emb16 = (unsigned short*)(ws + take((size_t)Vsz * Esz * 2));
    size_t fixed = off;

    int TC = 128;
    while (TC > 1 && fixed + (size_t)TC * Bsz * G4H * 2 > ws_size) TC >>= 1;
    unsigned short* xp = (unsigned short*)(ws + take((size_t)TC * Bsz * G4H * 2));

    k_prep_emb<<<(Vsz * Esz + 255) / 256, 256, 0, stream>>>(emb, emb16);
    k_prep_w<<<(4 * Hsz * Esz + 255) / 256, 256, 0, stream>>>(W_ii, W_if, W_ig, W_io, Esz, Wi16);
    k_prep_w<<<(4 * Hsz * Hsz + 255) / 256, 256, 0, stream>>>(W_hi, W_hf, W_hg, W_ho, Hsz, Wh16);
    k_prep_misc<<<(2 * BH + 255) / 256, 256, 0, stream>>>(b_i, b_f, b_g, b_o, b4, ghbuf, cbuf, outh, bar);

    for (int c = 0; c < Tsz / TC; ++c) {
        dim3 g(TC, 32);
        xp_gemm<<<g, 256, 0, stream>>>(emb16, Wi16, b4, x, xp, c * TC);
        lstm_steps<<<NB, 256, 0, stream>>>(Wh16, xp, lengths, ghbuf, cbuf, outh, bar, c * TC, TC);
    }
    k_fc<<<Bsz, 64, 0, stream>>>(outh, fc_w, fc_b, out);
}